// Round 2
// baseline (291.751 us; speedup 1.0000x reference)
//
#include <hip/hip_runtime.h>
#include <hip/hip_bf16.h>
#include <hip/hip_fp16.h>

// Problem constants (from setup_inputs): B=4, T=4096, D=1024, H=1024
#define B_ 4
#define T_ 4096
#define D_ 1024
#define H_ 1024
#define M_ (B_ * T_)   // 16384

typedef __attribute__((ext_vector_type(8))) short short8;   // 8 bf16 = 4 VGPRs (MFMA A/B frag)
typedef __attribute__((ext_vector_type(4))) float f32x4;    // MFMA C/D frag

// ---------------- fp32 -> bf16 (RNE) ----------------
__device__ __forceinline__ unsigned short f2bf(float f) {
    unsigned int u = __float_as_uint(f);
    u += 0x7fffu + ((u >> 16) & 1u);
    return (unsigned short)(u >> 16);
}

// One kernel converts x -> xb and Wz/Wh -> interleaved wcb.
// wcb int-row layout: 32-row groups; rows [32a..32a+15] = Wz[16a..16a+15],
// rows [32a+16..32a+31] = Wh[16a..16a+15]. This turns the dual GEMM into a
// single GEMM with N_int=2048 where even/odd 16-col fragments are (z,h) pairs.
__global__ __launch_bounds__(256) void convert_all(
    const float* __restrict__ x, const float* __restrict__ wz, const float* __restrict__ wh,
    unsigned short* __restrict__ xb, unsigned short* __restrict__ wcb)
{
    int i = blockIdx.x * 256 + threadIdx.x;
    const float* s; unsigned short* d; int soff; int doff;
    if (i < 4194304) {
        s = x; d = xb; soff = i; doff = i;
    } else if (i < 4456448) {
        int off = i - 4194304;          // float4 index within Wz
        int j = off >> 8; int k4 = off & 255;   // 256 float4 per row
        int ic = ((j >> 4) << 5) + (j & 15);
        s = wz; d = wcb; soff = off; doff = ic * 256 + k4;
    } else {
        int off = i - 4456448;
        int j = off >> 8; int k4 = off & 255;
        int ic = ((j >> 4) << 5) + 16 + (j & 15);
        s = wh; d = wcb; soff = off; doff = ic * 256 + k4;
    }
    float4 f = ((const float4*)s)[soff];
    ushort4 u;
    u.x = f2bf(f.x); u.y = f2bf(f.y); u.z = f2bf(f.z); u.w = f2bf(f.w);
    ((ushort4*)d)[doff] = u;
}

// async global->LDS, 16B per lane; LDS dest = wave-uniform base + lane*16
__device__ __forceinline__ void async16(const void* g, void* l) {
    __builtin_amdgcn_global_load_lds(
        (__attribute__((address_space(1))) void*)g,
        (__attribute__((address_space(3))) void*)l,
        16, 0, 0);
}

#define BARRIER() do { asm volatile("" ::: "memory"); __builtin_amdgcn_s_barrier(); asm volatile("" ::: "memory"); } while (0)
#define VMW(n)    asm volatile("s_waitcnt vmcnt(" #n ")" ::: "memory")

// ---------------- fused GEMM + epilogue + chunk summary (2 blocks/CU) ----------------
// Tile 128(M) x 128(N_int = 64 real H cols, z/h interleaved). BK=64, 4 waves (2M x 2N).
// LDS: fragment-order subtiles (16 rows x 32 k, lane-ordered => conflict-free ds_read_b128),
// [buf(2)][khalf(2)][subtile(8)][lane(64)] short8, A 32 KB + B 32 KB = 64 KB total
// => 2 resident blocks/CU (independent barrier domains -> cross-block latency hiding, m114).
// K-tile = 2 phases (one per k-half): {8 ds_read_b128; stage next tile's same k-half
// (4 async16: A x2 + B x2); barrier; setprio(1); 16 MFMA; setprio(0); VMW(4); barrier}.
// VMW(4) = counted wait, 2-phase issue->consume distance, never 0 in steady state (T4).
// WAR safety: stage into buffer p^1 slot (kh) happens >= 2 barriers after that slot's
// last reads completed (reads consumed pre-MFMA-barrier of the previous group).
__global__ __launch_bounds__(256, 2) void dual_gemm_kernel(
    const unsigned short* __restrict__ xb,   // [M][D] bf16
    const unsigned short* __restrict__ wcb,  // [2048][D] bf16, z/h interleaved by 16 rows
    const float* __restrict__ bz,
    const float* __restrict__ bh,
    __half2* __restrict__ av16,              // [M][H] half2(a,v)
    float2* __restrict__ chunkAV)            // [64][B][H]
{
    __shared__ short8 ldsA[2 * 2 * 8 * 64]; // 32 KB
    __shared__ short8 ldsB[2 * 2 * 8 * 64]; // 32 KB

    const int tid  = threadIdx.x;
    const int lane = tid & 63;
    const int w    = __builtin_amdgcn_readfirstlane(tid >> 6); // wave id 0..3 (SGPR)
    const int wr   = w >> 1;                 // 0..1  M-half of block
    const int wc   = w & 1;                  // 0..1  N-half of block
    const int r16  = lane & 15;
    const int q    = lane >> 4;

    // Bijective XCD swizzle (2048 % 8 == 0): XCD x owns swz in [256x, 256x+256)
    // -> mb in [16x, 16x+16), nb fastest. A-panel per XCD = 16 x 256 KB = 4 MB (L2-fit).
    const int bid = blockIdx.x;
    const int swz = (bid & 7) * 256 + (bid >> 3);
    const int nb  = swz & 15;                // int-col block (128 int cols = 64 real)
    const int mb  = swz >> 4;                // 0..127

    // staging: wave w stages subtiles {2w, 2w+1} of each (A|B, kh) slot.
    // per-lane global source is frag-order permuted (row r16, k-piece q*8); LDS dest linear.
    const int laneoff = r16 * D_ + q * 8;
    const unsigned short* gA = xb  + (size_t)(mb * 128 + 2 * w * 16) * D_ + laneoff;
    const unsigned short* gB = wcb + (size_t)(nb * 128 + 2 * w * 16) * D_ + laneoff;

#define STAGE_AB(tt, kh, pp) do { \
    const unsigned short* _sa = gA + (tt) * 64 + (kh) * 32; \
    const unsigned short* _sb = gB + (tt) * 64 + (kh) * 32; \
    short8* _da = &ldsA[((pp) * 2 + (kh)) * 512 + 2 * w * 64]; \
    short8* _db = &ldsB[((pp) * 2 + (kh)) * 512 + 2 * w * 64]; \
    async16(_sa, _da); async16(_sa + 16 * D_, _da + 64); \
    async16(_sb, _db); async16(_sb + 16 * D_, _db + 64); } while (0)

    f32x4 acc[4][4] = {};

    // prologue: tile 0, both k-halves (8 loads/wave); force k0 (oldest 4) landed.
    STAGE_AB(0, 0, 0);
    STAGE_AB(0, 1, 0);
    VMW(4);
    BARRIER();

    short8 fa[4], fb[4];

#define MFMA16() do { \
    _Pragma("unroll") \
    for (int m = 0; m < 4; ++m) { \
        _Pragma("unroll") \
        for (int n = 0; n < 4; ++n) \
            acc[m][n] = __builtin_amdgcn_mfma_f32_16x16x32_bf16( \
                fa[m], fb[n], acc[m][n], 0, 0, 0); \
    } } while (0)

    for (int g = 0; g < 16; ++g) {
        const int p = g & 1;

        // ---- phase alpha: k-half 0 ----
        {
            const int sA = (p * 2 + 0) * 512 + wr * 256;
            const int sB = (p * 2 + 0) * 512 + wc * 256;
#pragma unroll
            for (int m = 0; m < 4; ++m) fa[m] = ldsA[sA + m * 64 + lane];
#pragma unroll
            for (int n = 0; n < 4; ++n) fb[n] = ldsB[sB + n * 64 + lane];
        }
        if (g < 15) STAGE_AB(g + 1, 0, p ^ 1);
        BARRIER();
        __builtin_amdgcn_s_setprio(1);
        MFMA16();
        __builtin_amdgcn_s_setprio(0);
        if (g < 15) { VMW(4); } else { VMW(0); }   // force t_g k1 landed for phase beta
        BARRIER();

        // ---- phase beta: k-half 1 ----
        {
            const int sA = (p * 2 + 1) * 512 + wr * 256;
            const int sB = (p * 2 + 1) * 512 + wc * 256;
#pragma unroll
            for (int m = 0; m < 4; ++m) fa[m] = ldsA[sA + m * 64 + lane];
#pragma unroll
            for (int n = 0; n < 4; ++n) fb[n] = ldsB[sB + n * 64 + lane];
        }
        if (g < 15) STAGE_AB(g + 1, 1, p ^ 1);
        BARRIER();
        __builtin_amdgcn_s_setprio(1);
        MFMA16();
        __builtin_amdgcn_s_setprio(0);
        if (g < 15) VMW(4);                        // force t_{g+1} k0 landed for next alpha
        BARRIER();
    }

    // ---------------- epilogue ----------------
    // C/D layout: col = lane&15, row = q*4 + rr  [verified m89/m91].
    // acc[mf][2*gg+0] = z-GEMM, acc[mf][2*gg+1] = h-GEMM for real col
    //   ncol = nb*64 + wc*32 + gg*16 + r16; rows m = mb*128 + wr*64 + mf*16 + q*4 + rr.
    // Each wave owns exactly one 64-row chunk: cglob = mb*2 + wr.
    const int mrow0 = mb * 128 + wr * 64;
    const int cglob = mb * 2 + wr;           // global 64-row chunk id, 0..255
#pragma unroll
    for (int gg = 0; gg < 2; ++gg) {
        const int ncol = nb * 64 + wc * 32 + gg * 16 + r16;
        const float bzv = bz[ncol];
        const float bhv = bh[ncol];
        float CA = 1.0f, CV = 0.0f;          // chunk composite (64 rows)
#pragma unroll
        for (int mf = 0; mf < 4; ++mf) {
            float LA = 1.0f, LV = 0.0f;      // this lane's 4-row segment
#pragma unroll
            for (int rr = 0; rr < 4; ++rr) {
                float kv = acc[mf][2 * gg + 0][rr] + bzv;
                float hv = acc[mf][2 * gg + 1][rr] + bhv;
                float tk = __expf(-fabsf(kv));
                float ik = 1.0f / (1.0f + tk);
                float sig = (kv >= 0.0f) ? ik : tk * ik;         // sigmoid(k)
                float ac  = (kv >= 0.0f) ? tk * ik : ik;         // sigmoid(-k)
                float th = __expf(-fabsf(hv));
                float ih = 1.0f / (1.0f + th);
                float gh = (hv >= 0.0f) ? (hv + 0.5f) : th * ih; // g(hb)
                float vv = sig * gh;
                const size_t m = (size_t)(mrow0 + mf * 16 + q * 4 + rr);
                av16[m * H_ + ncol] = __floats2half2_rn(ac, vv);
                LV = ac * LV + vv;           // ascending t composition
                LA = ac * LA;
            }
            // order-preserving combine across q (lower lane index = earlier rows)
#pragma unroll
            for (int mask = 16; mask <= 32; mask <<= 1) {
                float PA = __shfl_xor(LA, mask);
                float PV = __shfl_xor(LV, mask);
                if (lane & mask) { LV = LA * PV + LV; LA = LA * PA; }
                else             { LV = PA * LV + PV; LA = PA * LA; }
            }
            CV = LA * CV + LV;
            CA = LA * CA;
        }
        if (q == 0)
            chunkAV[(cglob & 63) * 4096 + (cglob >> 6) * 1024 + ncol] = make_float2(CA, CV);
    }
#undef STAGE_AB
#undef MFMA16
}

// ---------------- scan pass2: sequential over 64 chunk summaries per channel ----------------
__global__ __launch_bounds__(256) void scan_pass2(const float2* __restrict__ chunkAV,
                                                  const float* __restrict__ h0,
                                                  float* __restrict__ hstart) {
    int chan = blockIdx.x * blockDim.x + threadIdx.x;   // 4096 threads
    int n = chan & (H_ - 1);
    int b = chan >> 10;
    float x = h0[b * H_ + n];
    float h;
    if (x >= 0.0f) { h = x + 0.5f; }
    else { float t = __expf(x); h = t / (1.0f + t); }   // g(h0)
#pragma unroll 8
    for (int c = 0; c < 64; ++c) {
        hstart[c * 4096 + chan] = h;
        float2 s = chunkAV[c * 4096 + chan];
        h = s.x * h + s.y;
    }
}

// ---------------- scan pass3: replay each chunk from entry state ----------------
__global__ __launch_bounds__(256) void scan_pass3(const __half2* __restrict__ av16,
                                                  const float* __restrict__ hstart,
                                                  float* __restrict__ out) {
    int g = blockIdx.x * blockDim.x + threadIdx.x;
    int n = g & (H_ - 1);
    int rest = g >> 10;
    int c = rest & 63;
    int b = rest >> 6;
    float h = hstart[c * 4096 + b * 1024 + n];
    const __half2* base = av16 + ((size_t)(b * T_ + c * 64)) * H_ + n;
    float* obase = out + ((size_t)(b * T_ + c * 64)) * H_ + n;
#pragma unroll 8
    for (int t = 0; t < 64; ++t) {
        float2 p = __half22float2(base[(size_t)t * H_]);
        h = p.x * h + p.y;
        obase[(size_t)t * H_] = h;
    }
}

// ---------------- launch ----------------
extern "C" void kernel_launch(void* const* d_in, const int* in_sizes, int n_in,
                              void* d_out, int out_size, void* d_ws, size_t ws_size,
                              hipStream_t stream) {
    const float* x  = (const float*)d_in[0];   // [B,T,D]
    const float* h0 = (const float*)d_in[1];   // [B,H]
    const float* Wz = (const float*)d_in[2];   // [H,D]
    const float* bz = (const float*)d_in[3];   // [H]
    const float* Wh = (const float*)d_in[4];   // [H,D]
    const float* bh = (const float*)d_in[5];   // [H]
    float* out = (float*)d_out;

    // workspace layout (bytes):
    //   xb  bf16 [M][D]            @ 0            33,554,432
    //   wcb bf16 [2048][D]         @ 33554432      4,194,304
    //   av16 half2 [M][H]          @ 37748736     67,108,864
    //   chunkAV float2 [64][B][H]  @ 104857600     2,097,152
    //   hstart fp32 [64][B*H]      @ 106954752     1,048,576
    char* ws = (char*)d_ws;
    unsigned short* xb  = (unsigned short*)(ws);
    unsigned short* wcb = (unsigned short*)(ws + 33554432);
    __half2* av16       = (__half2*)(ws + 37748736);
    float2* chunkAV     = (float2*)(ws + 104857600);
    float*  hstart      = (float*)(ws + 106954752);

    convert_all<<<18432, 256, 0, stream>>>(x, Wz, Wh, xb, wcb);

    dual_gemm_kernel<<<2048, 256, 0, stream>>>(xb, wcb, bz, bh, av16, chunkAV);

    scan_pass2<<<16,   256, 0, stream>>>(chunkAV, h0, hstart);
    scan_pass3<<<1024, 256, 0, stream>>>(av16, hstart, out);
}

// Round 3
// 272.429 us; speedup vs baseline: 1.0709x; 1.0709x over previous
//
#include <hip/hip_runtime.h>
#include <hip/hip_bf16.h>
#include <hip/hip_fp16.h>

// Problem constants (from setup_inputs): B=4, T=4096, D=1024, H=1024
#define B_ 4
#define T_ 4096
#define D_ 1024
#define H_ 1024
#define M_ (B_ * T_)   // 16384

typedef __attribute__((ext_vector_type(8))) short short8;   // 8 bf16 = 4 VGPRs (MFMA A/B frag)
typedef __attribute__((ext_vector_type(4))) float f32x4;    // MFMA C/D frag

// ---------------- fp32 -> bf16 (RNE) ----------------
__device__ __forceinline__ unsigned short f2bf(float f) {
    unsigned int u = __float_as_uint(f);
    u += 0x7fffu + ((u >> 16) & 1u);
    return (unsigned short)(u >> 16);
}

// One kernel converts x -> xb and Wz/Wh -> interleaved wcb.
// wcb int-row layout: 32-row groups; rows [32a..32a+15] = Wz[16a..16a+15],
// rows [32a+16..32a+31] = Wh[16a..16a+15]. This turns the dual GEMM into a
// single GEMM with N_int=2048 where even/odd 16-col fragments are (z,h) pairs.
__global__ __launch_bounds__(256) void convert_all(
    const float* __restrict__ x, const float* __restrict__ wz, const float* __restrict__ wh,
    unsigned short* __restrict__ xb, unsigned short* __restrict__ wcb)
{
    int i = blockIdx.x * 256 + threadIdx.x;
    const float* s; unsigned short* d; int soff; int doff;
    if (i < 4194304) {
        s = x; d = xb; soff = i; doff = i;
    } else if (i < 4456448) {
        int off = i - 4194304;          // float4 index within Wz
        int j = off >> 8; int k4 = off & 255;   // 256 float4 per row
        int ic = ((j >> 4) << 5) + (j & 15);
        s = wz; d = wcb; soff = off; doff = ic * 256 + k4;
    } else {
        int off = i - 4456448;
        int j = off >> 8; int k4 = off & 255;
        int ic = ((j >> 4) << 5) + 16 + (j & 15);
        s = wh; d = wcb; soff = off; doff = ic * 256 + k4;
    }
    float4 f = ((const float4*)s)[soff];
    ushort4 u;
    u.x = f2bf(f.x); u.y = f2bf(f.y); u.z = f2bf(f.z); u.w = f2bf(f.w);
    ((ushort4*)d)[doff] = u;
}

// async global->LDS, 16B per lane; LDS dest = wave-uniform base + lane*16
__device__ __forceinline__ void async16(const void* g, void* l) {
    __builtin_amdgcn_global_load_lds(
        (__attribute__((address_space(1))) void*)g,
        (__attribute__((address_space(3))) void*)l,
        16, 0, 0);
}

#define BARRIER() do { asm volatile("" ::: "memory"); __builtin_amdgcn_s_barrier(); asm volatile("" ::: "memory"); } while (0)
#define VMW(n)    asm volatile("s_waitcnt vmcnt(" #n ")" ::: "memory")

// ---------------- fused GEMM (fused K-tile phase, counted vmcnt) ----------------
// Tile 256(M) x 256(N_int = 128 real H cols, z/h interleaved). BK=64, 8 waves (2M x 4N).
// LDS: fragment-order subtiles (16 rows x 32 k, lane-ordered => conflict-free ds_read_b128),
// [buf(2)][khalf(2)][subtile(16)][lane(64)] short8 A and B = 64 KB + 64 KB = 128 KB.
// ONE phase per K-tile (vs R1's 4): per group g:
//   {stage tile g+1 (8 async16/wave); VMW(8) -> tile g landed (distance = 1 full group,
//    ~3-4k cyc); barrier; setprio(1); 24 ds_read_b128 + 64 MFMA (compiler-scheduled,
//    quadrant-local frag arrays); setprio(0); barrier}
// => 2 barriers + 1 counted wait per 64 wave-MFMAs (R1 had 8 barriers + 2 waits).
// WAR safety: stage into buf p^1 at top of group g; p^1 was last ds_read in group g-1,
// and those reads completed before their consuming MFMAs issued (in-order), hence before
// group g-1's closing barrier, which all waves crossed before any stage of group g.
__global__ __launch_bounds__(512, 2) void dual_gemm_kernel(
    const unsigned short* __restrict__ xb,   // [M][D] bf16
    const unsigned short* __restrict__ wcb,  // [2048][D] bf16, z/h interleaved by 16 rows
    const float* __restrict__ bz,
    const float* __restrict__ bh,
    __half2* __restrict__ av16,              // [M][H] half2(a,v)
    float2* __restrict__ chunkAV)            // [64][B][H]
{
    __shared__ short8 ldsA[2 * 2 * 16 * 64]; // 64 KB
    __shared__ short8 ldsB[2 * 2 * 16 * 64]; // 64 KB

    const int tid  = threadIdx.x;
    const int lane = tid & 63;
    const int w    = __builtin_amdgcn_readfirstlane(tid >> 6); // wave id 0..7 (SGPR)
    const int wr   = w >> 2;                 // 0..1  M-half of block
    const int wc   = w & 3;                  // 0..3  N-quarter of block
    const int r16  = lane & 15;
    const int q    = lane >> 4;

    // Bijective XCD swizzle (512 % 8 == 0): XCD x owns mb in [8x, 8x+8), nb fastest.
    const int bid = blockIdx.x;
    const int swz = (bid & 7) * 64 + (bid >> 3);
    const int nb  = swz & 7;                 // int-col block (256 int cols = 128 real)
    const int mb  = swz >> 3;                // 0..63

    // staging: wave w stages subtiles {2w, 2w+1} of every half-tile.
    // per-lane global source is frag-order permuted (row r16, k-piece q*8); LDS dest linear.
    const int laneoff = r16 * D_ + q * 8;
    const unsigned short* gA = xb  + (size_t)(mb * 256 + 2 * w * 16) * D_ + laneoff;
    const unsigned short* gB = wcb + (size_t)(nb * 256 + 2 * w * 16) * D_ + laneoff;

#define STAGE_A(tt, kh, pp) do { \
    const unsigned short* _s = gA + (tt) * 64 + (kh) * 32; \
    short8* _d = &ldsA[(pp) * 2048 + (kh) * 1024 + 2 * w * 64]; \
    async16(_s, _d); \
    async16(_s + 16 * D_, _d + 64); } while (0)
#define STAGE_B(tt, kh, pp) do { \
    const unsigned short* _s = gB + (tt) * 64 + (kh) * 32; \
    short8* _d = &ldsB[(pp) * 2048 + (kh) * 1024 + 2 * w * 64]; \
    async16(_s, _d); \
    async16(_s + 16 * D_, _d + 64); } while (0)

    f32x4 acc[8][4] = {};

    // prologue: stage tile 0 fully (8 loads/wave); no wait here — group 0's VMW(8)
    // (after staging tile 1) forces exactly these 8 oldest loads complete.
    STAGE_A(0, 0, 0); STAGE_B(0, 0, 0);
    STAGE_A(0, 1, 0); STAGE_B(0, 1, 0);

    for (int g = 0; g < 16; ++g) {
        const int p  = g & 1;
        const int oA = p * 2048 + wr * 512;  // wave-uniform (SGPR) LDS bases
        const int oB = p * 2048 + wc * 256;

        if (g < 15) {
            STAGE_A(g + 1, 0, p ^ 1);
            STAGE_B(g + 1, 0, p ^ 1);
            STAGE_A(g + 1, 1, p ^ 1);
            STAGE_B(g + 1, 1, p ^ 1);
            VMW(8);                          // tile g's 8 loads done; tile g+1's stay in flight
        } else {
            VMW(0);                          // last tile: drain
        }
        BARRIER();

        __builtin_amdgcn_s_setprio(1);
        {
            // ---- k-half 0: both m-halves (fb shared) ----
            short8 fb0[4], fa0[4], fa1[4];
#pragma unroll
            for (int n = 0; n < 4; ++n) fb0[n] = ldsB[oB + n * 64 + lane];
#pragma unroll
            for (int m = 0; m < 4; ++m) fa0[m] = ldsA[oA + m * 64 + lane];
#pragma unroll
            for (int m = 0; m < 4; ++m) fa1[m] = ldsA[oA + (4 + m) * 64 + lane];
#pragma unroll
            for (int m = 0; m < 4; ++m)
#pragma unroll
                for (int n = 0; n < 4; ++n)
                    acc[m][n] = __builtin_amdgcn_mfma_f32_16x16x32_bf16(fa0[m], fb0[n], acc[m][n], 0, 0, 0);
#pragma unroll
            for (int m = 0; m < 4; ++m)
#pragma unroll
                for (int n = 0; n < 4; ++n)
                    acc[4 + m][n] = __builtin_amdgcn_mfma_f32_16x16x32_bf16(fa1[m], fb0[n], acc[4 + m][n], 0, 0, 0);

            // ---- k-half 1: both m-halves ----
            short8 fb1[4], fa2[4], fa3[4];
#pragma unroll
            for (int n = 0; n < 4; ++n) fb1[n] = ldsB[oB + 1024 + n * 64 + lane];
#pragma unroll
            for (int m = 0; m < 4; ++m) fa2[m] = ldsA[oA + 1024 + m * 64 + lane];
#pragma unroll
            for (int m = 0; m < 4; ++m) fa3[m] = ldsA[oA + 1024 + (4 + m) * 64 + lane];
#pragma unroll
            for (int m = 0; m < 4; ++m)
#pragma unroll
                for (int n = 0; n < 4; ++n)
                    acc[m][n] = __builtin_amdgcn_mfma_f32_16x16x32_bf16(fa2[m], fb1[n], acc[m][n], 0, 0, 0);
#pragma unroll
            for (int m = 0; m < 4; ++m)
#pragma unroll
                for (int n = 0; n < 4; ++n)
                    acc[4 + m][n] = __builtin_amdgcn_mfma_f32_16x16x32_bf16(fa3[m], fb1[n], acc[4 + m][n], 0, 0, 0);
        }
        __builtin_amdgcn_s_setprio(0);
        BARRIER();
    }

    // ---------------- epilogue ----------------
    // C/D layout: col = lane&15, row = q*4 + rr  [verified m89/m91].
    // acc[mf][2*gg+0] = z-GEMM, acc[mf][2*gg+1] = h-GEMM for real col
    //   ncol = nb*128 + wc*32 + gg*16 + r16; rows m = mb*256 + wr*128 + mf*16 + q*4 + rr.
    const int mrow0 = mb * 256 + wr * 128;
#pragma unroll
    for (int gg = 0; gg < 2; ++gg) {
        const int ncol = nb * 128 + wc * 32 + gg * 16 + r16;
        const float bzv = bz[ncol];
        const float bhv = bh[ncol];
#pragma unroll
        for (int hh = 0; hh < 2; ++hh) {     // two 64-row chunks per wave
            float CA = 1.0f, CV = 0.0f;
#pragma unroll
            for (int mm = 0; mm < 4; ++mm) {
                const int mf = hh * 4 + mm;
                float LA = 1.0f, LV = 0.0f;  // this lane's 4-row segment
#pragma unroll
                for (int rr = 0; rr < 4; ++rr) {
                    float kv = acc[mf][2 * gg + 0][rr] + bzv;
                    float hv = acc[mf][2 * gg + 1][rr] + bhv;
                    float tk = __expf(-fabsf(kv));
                    float ik = 1.0f / (1.0f + tk);
                    float sig = (kv >= 0.0f) ? ik : tk * ik;         // sigmoid(k)
                    float ac  = (kv >= 0.0f) ? tk * ik : ik;         // sigmoid(-k)
                    float th = __expf(-fabsf(hv));
                    float ih = 1.0f / (1.0f + th);
                    float gh = (hv >= 0.0f) ? (hv + 0.5f) : th * ih; // g(hb)
                    float vv = sig * gh;
                    const size_t m = (size_t)(mrow0 + mf * 16 + q * 4 + rr);
                    av16[m * H_ + ncol] = __floats2half2_rn(ac, vv);
                    LV = ac * LV + vv;       // ascending t composition
                    LA = ac * LA;
                }
                // order-preserving combine across q (lower lane index = earlier rows)
#pragma unroll
                for (int mask = 16; mask <= 32; mask <<= 1) {
                    float PA = __shfl_xor(LA, mask);
                    float PV = __shfl_xor(LV, mask);
                    if (lane & mask) { LV = LA * PV + LV; LA = LA * PA; }
                    else             { LV = PA * LV + PV; LA = PA * LA; }
                }
                CV = LA * CV + LV;
                CA = LA * CA;
            }
            if (q == 0) {
                const int cglob = mb * 4 + wr * 2 + hh;   // global 64-row chunk id 0..255
                chunkAV[(cglob & 63) * 4096 + (cglob >> 6) * 1024 + ncol] = make_float2(CA, CV);
            }
        }
    }
#undef STAGE_A
#undef STAGE_B
}

// ---------------- scan pass2: sequential over 64 chunk summaries per channel ----------------
__global__ __launch_bounds__(256) void scan_pass2(const float2* __restrict__ chunkAV,
                                                  const float* __restrict__ h0,
                                                  float* __restrict__ hstart) {
    int chan = blockIdx.x * blockDim.x + threadIdx.x;   // 4096 threads
    int n = chan & (H_ - 1);
    int b = chan >> 10;
    float x = h0[b * H_ + n];
    float h;
    if (x >= 0.0f) { h = x + 0.5f; }
    else { float t = __expf(x); h = t / (1.0f + t); }   // g(h0)
#pragma unroll 8
    for (int c = 0; c < 64; ++c) {
        hstart[c * 4096 + chan] = h;
        float2 s = chunkAV[c * 4096 + chan];
        h = s.x * h + s.y;
    }
}

// ---------------- scan pass3: replay each chunk from entry state ----------------
__global__ __launch_bounds__(256) void scan_pass3(const __half2* __restrict__ av16,
                                                  const float* __restrict__ hstart,
                                                  float* __restrict__ out) {
    int g = blockIdx.x * blockDim.x + threadIdx.x;
    int n = g & (H_ - 1);
    int rest = g >> 10;
    int c = rest & 63;
    int b = rest >> 6;
    float h = hstart[c * 4096 + b * 1024 + n];
    const __half2* base = av16 + ((size_t)(b * T_ + c * 64)) * H_ + n;
    float* obase = out + ((size_t)(b * T_ + c * 64)) * H_ + n;
#pragma unroll 8
    for (int t = 0; t < 64; ++t) {
        float2 p = __half22float2(base[(size_t)t * H_]);
        h = p.x * h + p.y;
        obase[(size_t)t * H_] = h;
    }
}

// ---------------- launch ----------------
extern "C" void kernel_launch(void* const* d_in, const int* in_sizes, int n_in,
                              void* d_out, int out_size, void* d_ws, size_t ws_size,
                              hipStream_t stream) {
    const float* x  = (const float*)d_in[0];   // [B,T,D]
    const float* h0 = (const float*)d_in[1];   // [B,H]
    const float* Wz = (const float*)d_in[2];   // [H,D]
    const float* bz = (const float*)d_in[3];   // [H]
    const float* Wh = (const float*)d_in[4];   // [H,D]
    const float* bh = (const float*)d_in[5];   // [H]
    float* out = (float*)d_out;

    // workspace layout (bytes):
    //   xb  bf16 [M][D]            @ 0            33,554,432
    //   wcb bf16 [2048][D]         @ 33554432      4,194,304
    //   av16 half2 [M][H]          @ 37748736     67,108,864
    //   chunkAV float2 [64][B][H]  @ 104857600     2,097,152
    //   hstart fp32 [64][B*H]      @ 106954752     1,048,576
    char* ws = (char*)d_ws;
    unsigned short* xb  = (unsigned short*)(ws);
    unsigned short* wcb = (unsigned short*)(ws + 33554432);
    __half2* av16       = (__half2*)(ws + 37748736);
    float2* chunkAV     = (float2*)(ws + 104857600);
    float*  hstart      = (float*)(ws + 106954752);

    convert_all<<<18432, 256, 0, stream>>>(x, Wz, Wh, xb, wcb);

    dual_gemm_kernel<<<512, 512, 0, stream>>>(xb, wcb, bz, bh, av16, chunkAV);

    scan_pass2<<<16,   256, 0, stream>>>(chunkAV, h0, hstart);
    scan_pass3<<<1024, 256, 0, stream>>>(av16, hstart, out);
}

// Round 4
// 242.197 us; speedup vs baseline: 1.2046x; 1.1248x over previous
//
#include <hip/hip_runtime.h>
#include <hip/hip_bf16.h>
#include <hip/hip_fp16.h>

// Problem constants (from setup_inputs): B=4, T=4096, D=1024, H=1024
#define B_ 4
#define T_ 4096
#define D_ 1024
#define H_ 1024
#define M_ (B_ * T_)   // 16384

typedef __attribute__((ext_vector_type(8))) short short8;   // 8 bf16 = 4 VGPRs (MFMA A/B frag)
typedef __attribute__((ext_vector_type(4))) float f32x4;    // MFMA C/D frag

// ---------------- fp32 -> bf16 (RNE) ----------------
__device__ __forceinline__ unsigned short f2bf(float f) {
    unsigned int u = __float_as_uint(f);
    u += 0x7fffu + ((u >> 16) & 1u);
    return (unsigned short)(u >> 16);
}

// Convert + PERMUTE into fragment-subtile-lane order.
// Layout: subtile = 16 rows x 32 k of the (row-major) source; subtile s = r*32 + c
// (r = row-block, c = k-block). Within a subtile: lane l = (row = l&15, kpiece = l>>4),
// 8 contiguous bf16 per lane. Linear: elem_offset = (s*64 + l)*8.
// => GEMM staging / B-frag loads read CONTIGUOUS 1KB (lane*16B) instead of a
//    16-segment x 64B gather. Gather cost is paid HERE (reads merge to full lines
//    within each wave: threads l, l+16, l+32, l+48 share one 128B line).
// wcb int-row interleave unchanged: int-row ir -> Wz row (ir>>5)*16 + (ir&15) if
// (ir&31)<16 else Wh row (ir>>5)*16 + (ir&31) - 16.
__global__ __launch_bounds__(256) void convert_all(
    const float* __restrict__ x, const float* __restrict__ wz, const float* __restrict__ wh,
    unsigned short* __restrict__ xbp, unsigned short* __restrict__ wcbp)
{
    int i = blockIdx.x * 256 + threadIdx.x;
    const float* srcrow;
    unsigned short* dst;
    if (i < 2097152) {               // x: 16384x1024 -> 2,097,152 lane-slots
        int l = i & 63, s = i >> 6;
        int c = s & 31, r = s >> 5;  // r 0..1023
        int row = r * 16 + (l & 15);
        int k   = c * 32 + (l >> 4) * 8;
        srcrow = x + (size_t)row * D_ + k;
        dst = xbp + (size_t)i * 8;
    } else {                         // wcb: 2048x1024 -> 262,144 lane-slots
        int j = i - 2097152;
        int l = j & 63, s = j >> 6;
        int c = s & 31, r = s >> 5;  // r 0..127
        int ir = r * 16 + (l & 15);  // interleaved int-row 0..2047
        int a = ir >> 5, wi = ir & 31;
        const float* m = (wi < 16) ? wz : wh;
        int srow = a * 16 + (wi & 15);
        int k = c * 32 + (l >> 4) * 8;
        srcrow = m + (size_t)srow * D_ + k;
        dst = wcbp + (size_t)j * 8;
    }
    float4 f0 = ((const float4*)srcrow)[0];
    float4 f1 = ((const float4*)srcrow)[1];
    ushort4 u0, u1;
    u0.x = f2bf(f0.x); u0.y = f2bf(f0.y); u0.z = f2bf(f0.z); u0.w = f2bf(f0.w);
    u1.x = f2bf(f1.x); u1.y = f2bf(f1.y); u1.z = f2bf(f1.z); u1.w = f2bf(f1.w);
    ((ushort4*)dst)[0] = u0;
    ((ushort4*)dst)[1] = u1;
}

// async global->LDS, 16B per lane; LDS dest = wave-uniform base + lane*16
__device__ __forceinline__ void async16(const void* g, void* l) {
    __builtin_amdgcn_global_load_lds(
        (__attribute__((address_space(1))) void*)g,
        (__attribute__((address_space(3))) void*)l,
        16, 0, 0);
}

#define BARRIER() do { asm volatile("" ::: "memory"); __builtin_amdgcn_s_barrier(); asm volatile("" ::: "memory"); } while (0)
#define VMW(n)    asm volatile("s_waitcnt vmcnt(" #n ")" ::: "memory")

// ---------------- fused GEMM + epilogue + chunk summary ----------------
// R3 schedule kept (1 fused phase per K-tile, 2 barriers, counted vmcnt). Changes:
//  * xb/wcb pre-permuted => async16 sources are CONTIGUOUS 1KB (no TA gather).
//  * B direct-to-registers (no ldsB): 8 contiguous dwordx4 per wave per K-tile,
//    ping-pong double buffer (static indexing), from L2-resident 4MB wcbp.
//  * LDS = A only, 64KB double-buffered; per K-tile LDS: 32KB DMA-write + 128KB read.
// Counted wait: GROUP(g) issues A(g+1) 4 async16 + B(g+1) 8 loads, then VMW(12)
// => everything older (A(g), B(g)) complete. Never 0 in steady state.
// WAR: buf p^1 re-staged in GROUP(g) after GROUP(g-1)'s closing barrier; its reads
// completed before that barrier (in-order lgkm before consuming MFMAs).
__global__ __launch_bounds__(512, 2) void dual_gemm_kernel(
    const unsigned short* __restrict__ xbp,  // permuted [1024 rowblk][32 kblk][64][8]
    const unsigned short* __restrict__ wcbp, // permuted [128 rowblk][32 kblk][64][8]
    const float* __restrict__ bz,
    const float* __restrict__ bh,
    __half2* __restrict__ av16,              // [M][H] half2(a,v)
    float2* __restrict__ chunkAV)            // [64][B][H]
{
    __shared__ short8 ldsA[2 * 2 * 16 * 64]; // 64 KB: [buf][kh][16 subtiles][64 lanes]

    const int tid  = threadIdx.x;
    const int lane = tid & 63;
    const int w    = __builtin_amdgcn_readfirstlane(tid >> 6); // wave id 0..7 (SGPR)
    const int wr   = w >> 2;                 // 0..1  M-half of block
    const int wc   = w & 3;                  // 0..3  N-quarter of block
    const int r16  = lane & 15;
    const int q    = lane >> 4;

    // Bijective XCD swizzle (512 % 8 == 0): XCD x owns mb in [8x, 8x+8), nb fastest.
    const int bid = blockIdx.x;
    const int swz = (bid & 7) * 64 + (bid >> 3);
    const int nb  = swz & 7;                 // int-col block (256 int cols = 128 real)
    const int mb  = swz >> 3;                // 0..63

    // A staging bases (permuted layout): row-blocks mb*16 + {2w, 2w+1}, contiguous lane*16B.
    const unsigned short* gAp = xbp + ((size_t)mb * 16 * 32) * 512 + lane * 8;
    // B direct-load base: wave's 4 int-row-blocks start at nb*16 + wc*4.
    const unsigned short* gBd = wcbp + ((size_t)(nb * 16 + wc * 4) * 32) * 512 + lane * 8;

#define STAGE_A(tt, pp) do { \
    _Pragma("unroll") \
    for (int kh = 0; kh < 2; ++kh) { \
        _Pragma("unroll") \
        for (int d = 0; d < 2; ++d) { \
            const unsigned short* _s = gAp + (size_t)(((2 * w + d) * 32 + (tt) * 2 + kh)) * 512; \
            short8* _dst = &ldsA[(pp) * 2048 + kh * 1024 + (2 * w + d) * 64]; \
            async16(_s, _dst); \
        } } } while (0)

// B frag (n, kh) of tile tt: elem offset (n*32 + tt*2 + kh)*512 from gBd.
#define LOADB(DST, tt) do { \
    _Pragma("unroll") \
    for (int n = 0; n < 4; ++n) { \
        _Pragma("unroll") \
        for (int kh = 0; kh < 2; ++kh) { \
            DST[n][kh] = *(const short8*)(gBd + (size_t)((n * 32 + (tt) * 2 + kh)) * 512); \
        } } } while (0)

    f32x4 acc[8][4] = {};
    short8 fbA[4][2], fbB[4][2];

    // prologue: stage A(0) + load B(0). GROUP(0) stages A(1)/B(1).
    STAGE_A(0, 0);
    LOADB(fbA, 0);

#define GROUP(g, CUR, NXT) do { \
    const int _p = (g) & 1; \
    if ((g) < 15) { STAGE_A((g) + 1, _p ^ 1); LOADB(NXT, (g) + 1); VMW(12); } \
    else          { VMW(0); } \
    BARRIER(); \
    const int _oA = _p * 2048 + wr * 512; \
    { \
        short8 fa0[4], fa1[4]; \
        _Pragma("unroll") \
        for (int m = 0; m < 4; ++m) fa0[m] = ldsA[_oA + m * 64 + lane]; \
        _Pragma("unroll") \
        for (int m = 0; m < 4; ++m) fa1[m] = ldsA[_oA + (4 + m) * 64 + lane]; \
        __builtin_amdgcn_s_setprio(1); \
        _Pragma("unroll") \
        for (int m = 0; m < 4; ++m) \
            _Pragma("unroll") \
            for (int n = 0; n < 4; ++n) \
                acc[m][n] = __builtin_amdgcn_mfma_f32_16x16x32_bf16(fa0[m], CUR[n][0], acc[m][n], 0, 0, 0); \
        _Pragma("unroll") \
        for (int m = 0; m < 4; ++m) \
            _Pragma("unroll") \
            for (int n = 0; n < 4; ++n) \
                acc[4 + m][n] = __builtin_amdgcn_mfma_f32_16x16x32_bf16(fa1[m], CUR[n][0], acc[4 + m][n], 0, 0, 0); \
        __builtin_amdgcn_s_setprio(0); \
    } \
    { \
        short8 fa2[4], fa3[4]; \
        _Pragma("unroll") \
        for (int m = 0; m < 4; ++m) fa2[m] = ldsA[_oA + 1024 + m * 64 + lane]; \
        _Pragma("unroll") \
        for (int m = 0; m < 4; ++m) fa3[m] = ldsA[_oA + 1024 + (4 + m) * 64 + lane]; \
        __builtin_amdgcn_s_setprio(1); \
        _Pragma("unroll") \
        for (int m = 0; m < 4; ++m) \
            _Pragma("unroll") \
            for (int n = 0; n < 4; ++n) \
                acc[m][n] = __builtin_amdgcn_mfma_f32_16x16x32_bf16(fa2[m], CUR[n][1], acc[m][n], 0, 0, 0); \
        _Pragma("unroll") \
        for (int m = 0; m < 4; ++m) \
            _Pragma("unroll") \
            for (int n = 0; n < 4; ++n) \
                acc[4 + m][n] = __builtin_amdgcn_mfma_f32_16x16x32_bf16(fa3[m], CUR[n][1], acc[4 + m][n], 0, 0, 0); \
        __builtin_amdgcn_s_setprio(0); \
    } \
    BARRIER(); \
} while (0)

    for (int it = 0; it < 8; ++it) {
        GROUP(2 * it,     fbA, fbB);
        GROUP(2 * it + 1, fbB, fbA);
    }

    // ---------------- epilogue (unchanged from R3) ----------------
    // C/D layout: col = lane&15, row = q*4 + rr  [verified m89/m91].
    // acc[mf][2*gg+0] = z-GEMM, acc[mf][2*gg+1] = h-GEMM for real col
    //   ncol = nb*128 + wc*32 + gg*16 + r16; rows m = mb*256 + wr*128 + mf*16 + q*4 + rr.
    const int mrow0 = mb * 256 + wr * 128;
#pragma unroll
    for (int gg = 0; gg < 2; ++gg) {
        const int ncol = nb * 128 + wc * 32 + gg * 16 + r16;
        const float bzv = bz[ncol];
        const float bhv = bh[ncol];
#pragma unroll
        for (int hh = 0; hh < 2; ++hh) {     // two 64-row chunks per wave
            float CA = 1.0f, CV = 0.0f;
#pragma unroll
            for (int mm = 0; mm < 4; ++mm) {
                const int mf = hh * 4 + mm;
                float LA = 1.0f, LV = 0.0f;  // this lane's 4-row segment
#pragma unroll
                for (int rr = 0; rr < 4; ++rr) {
                    float kv = acc[mf][2 * gg + 0][rr] + bzv;
                    float hv = acc[mf][2 * gg + 1][rr] + bhv;
                    float tk = __expf(-fabsf(kv));
                    float ik = 1.0f / (1.0f + tk);
                    float sig = (kv >= 0.0f) ? ik : tk * ik;         // sigmoid(k)
                    float ac  = (kv >= 0.0f) ? tk * ik : ik;         // sigmoid(-k)
                    float th = __expf(-fabsf(hv));
                    float ih = 1.0f / (1.0f + th);
                    float gh = (hv >= 0.0f) ? (hv + 0.5f) : th * ih; // g(hb)
                    float vv = sig * gh;
                    const size_t m = (size_t)(mrow0 + mf * 16 + q * 4 + rr);
                    av16[m * H_ + ncol] = __floats2half2_rn(ac, vv);
                    LV = ac * LV + vv;       // ascending t composition
                    LA = ac * LA;
                }
                // order-preserving combine across q (lower lane index = earlier rows)
#pragma unroll
                for (int mask = 16; mask <= 32; mask <<= 1) {
                    float PA = __shfl_xor(LA, mask);
                    float PV = __shfl_xor(LV, mask);
                    if (lane & mask) { LV = LA * PV + LV; LA = LA * PA; }
                    else             { LV = PA * LV + PV; LA = PA * LA; }
                }
                CV = LA * CV + LV;
                CA = LA * CA;
            }
            if (q == 0) {
                const int cglob = mb * 4 + wr * 2 + hh;   // global 64-row chunk id 0..255
                chunkAV[(cglob & 63) * 4096 + (cglob >> 6) * 1024 + ncol] = make_float2(CA, CV);
            }
        }
    }
#undef STAGE_A
#undef LOADB
#undef GROUP
}

// ---------------- scan pass2: sequential over 64 chunk summaries per channel ----------------
__global__ __launch_bounds__(256) void scan_pass2(const float2* __restrict__ chunkAV,
                                                  const float* __restrict__ h0,
                                                  float* __restrict__ hstart) {
    int chan = blockIdx.x * blockDim.x + threadIdx.x;   // 4096 threads
    int n = chan & (H_ - 1);
    int b = chan >> 10;
    float x = h0[b * H_ + n];
    float h;
    if (x >= 0.0f) { h = x + 0.5f; }
    else { float t = __expf(x); h = t / (1.0f + t); }   // g(h0)
#pragma unroll 8
    for (int c = 0; c < 64; ++c) {
        hstart[c * 4096 + chan] = h;
        float2 s = chunkAV[c * 4096 + chan];
        h = s.x * h + s.y;
    }
}

// ---------------- scan pass3: replay each chunk from entry state ----------------
__global__ __launch_bounds__(256) void scan_pass3(const __half2* __restrict__ av16,
                                                  const float* __restrict__ hstart,
                                                  float* __restrict__ out) {
    int g = blockIdx.x * blockDim.x + threadIdx.x;
    int n = g & (H_ - 1);
    int rest = g >> 10;
    int c = rest & 63;
    int b = rest >> 6;
    float h = hstart[c * 4096 + b * 1024 + n];
    const __half2* base = av16 + ((size_t)(b * T_ + c * 64)) * H_ + n;
    float* obase = out + ((size_t)(b * T_ + c * 64)) * H_ + n;
#pragma unroll 8
    for (int t = 0; t < 64; ++t) {
        float2 p = __half22float2(base[(size_t)t * H_]);
        h = p.x * h + p.y;
        obase[(size_t)t * H_] = h;
    }
}

// ---------------- launch ----------------
extern "C" void kernel_launch(void* const* d_in, const int* in_sizes, int n_in,
                              void* d_out, int out_size, void* d_ws, size_t ws_size,
                              hipStream_t stream) {
    const float* x  = (const float*)d_in[0];   // [B,T,D]
    const float* h0 = (const float*)d_in[1];   // [B,H]
    const float* Wz = (const float*)d_in[2];   // [H,D]
    const float* bz = (const float*)d_in[3];   // [H]
    const float* Wh = (const float*)d_in[4];   // [H,D]
    const float* bh = (const float*)d_in[5];   // [H]
    float* out = (float*)d_out;

    // workspace layout (bytes):
    //   xbp  bf16 perm [M][D]      @ 0            33,554,432
    //   wcbp bf16 perm [2048][D]   @ 33554432      4,194,304
    //   av16 half2 [M][H]          @ 37748736     67,108,864
    //   chunkAV float2 [64][B][H]  @ 104857600     2,097,152
    //   hstart fp32 [64][B*H]      @ 106954752     1,048,576
    char* ws = (char*)d_ws;
    unsigned short* xbp  = (unsigned short*)(ws);
    unsigned short* wcbp = (unsigned short*)(ws + 33554432);
    __half2* av16        = (__half2*)(ws + 37748736);
    float2* chunkAV      = (float2*)(ws + 104857600);
    float*  hstart       = (float*)(ws + 106954752);

    // 2,097,152 (x) + 262,144 (wcb) lane-slots = 2,359,296 threads = 9216 blocks
    convert_all<<<9216, 256, 0, stream>>>(x, Wz, Wh, xbp, wcbp);

    dual_gemm_kernel<<<512, 512, 0, stream>>>(xbp, wcbp, bz, bh, av16, chunkAV);

    scan_pass2<<<16,   256, 0, stream>>>(chunkAV, h0, hstart);
    scan_pass3<<<1024, 256, 0, stream>>>(av16, hstart, out);
}

// Round 5
// 239.582 us; speedup vs baseline: 1.2178x; 1.0109x over previous
//
#include <hip/hip_runtime.h>
#include <hip/hip_bf16.h>
#include <hip/hip_fp16.h>

// Problem constants (from setup_inputs): B=4, T=4096, D=1024, H=1024
#define B_ 4
#define T_ 4096
#define D_ 1024
#define H_ 1024
#define M_ (B_ * T_)   // 16384

typedef __attribute__((ext_vector_type(8))) short short8;   // 8 bf16 = 4 VGPRs (MFMA A/B frag)
typedef __attribute__((ext_vector_type(4))) float f32x4;    // MFMA C/D frag

// ---------------- fp32 -> bf16 (RNE) ----------------
__device__ __forceinline__ unsigned short f2bf(float f) {
    unsigned int u = __float_as_uint(f);
    u += 0x7fffu + ((u >> 16) & 1u);
    return (unsigned short)(u >> 16);
}

// Convert + PERMUTE into k-major fragment-subtile-lane order.
// Fragment subtile = 16 rows x 32 k; lane l = (row = l&15, kpiece = l>>4), 8 bf16/lane.
// K-MAJOR linear order: slot(c, rb, l) = (c*NRB + rb)*64 + l  (c = kblk 0..31).
// => in the GEMM, one kblk's fragments for consecutive row-blocks are CONTIGUOUS
//    1KB-apart => base + immediate-offset loads, one pointer bump per kblk.
// wcb int-row interleave: int-row ir -> Wz row (ir>>5)*16+(ir&15) if (ir&31)<16
// else Wh row (ir>>5)*16+(ir&31)-16  (even/odd 16-col output frags = (z,h) pairs).
__global__ __launch_bounds__(256) void convert_all(
    const float* __restrict__ x, const float* __restrict__ wz, const float* __restrict__ wh,
    unsigned short* __restrict__ xbp, unsigned short* __restrict__ wcbp)
{
    int i = blockIdx.x * 256 + threadIdx.x;
    const float* srcrow;
    unsigned short* dst;
    if (i < 2097152) {               // x: 16384x1024 -> 2,097,152 lane-slots
        int l = i & 63, s = i >> 6;
        int c = s & 31, r = s >> 5;  // r = rowblk 0..1023
        int row = r * 16 + (l & 15);
        int k   = c * 32 + (l >> 4) * 8;
        srcrow = x + (size_t)row * D_ + k;
        dst = xbp + ((size_t)(c * 1024 + r) * 64 + l) * 8;   // k-major
    } else {                         // wcb: 2048x1024 -> 262,144 lane-slots
        int j = i - 2097152;
        int l = j & 63, s = j >> 6;
        int c = s & 31, r = s >> 5;  // r = int-rowblk 0..127
        int ir = r * 16 + (l & 15);  // interleaved int-row 0..2047
        int a = ir >> 5, wi = ir & 31;
        const float* m = (wi < 16) ? wz : wh;
        int srow = a * 16 + (wi & 15);
        int k = c * 32 + (l >> 4) * 8;
        srcrow = m + (size_t)srow * D_ + k;
        dst = wcbp + ((size_t)(c * 128 + r) * 64 + l) * 8;   // k-major
    }
    float4 f0 = ((const float4*)srcrow)[0];
    float4 f1 = ((const float4*)srcrow)[1];
    ushort4 u0, u1;
    u0.x = f2bf(f0.x); u0.y = f2bf(f0.y); u0.z = f2bf(f0.z); u0.w = f2bf(f0.w);
    u1.x = f2bf(f1.x); u1.y = f2bf(f1.y); u1.z = f2bf(f1.z); u1.w = f2bf(f1.w);
    ((ushort4*)dst)[0] = u0;
    ((ushort4*)dst)[1] = u1;
}

// ---------------- fused GEMM, flatmm-style: NO LDS, NO BARRIERS ----------------
// Both operands pre-permuted to fragment-lane order => every fragment is one
// coalesced 1KB global_load_dwordx4 per wave. Each wave independently streams:
//   [load kblk c+1 frags] [32 MFMA on kblk c]   (explicit 2-set ping-pong)
// Wave tile: 128(M) x 64(N_int = 32 real cols); acc[8][4] = 128 regs (same shape
// and epilogue as R4). Block = 4 waves sharing one 128-row A panel (L1 reuse),
// wave w takes nbw = nbg*4 + w. Grid 1024 = 128 mbw x 8 nbg.
// XCD swizzle: XCD x owns mbw in [16x,16x+16) -> its A slice = 4 MB, L2-resident.
__global__ __launch_bounds__(256, 2) void dual_gemm_kernel(
    const unsigned short* __restrict__ xbp,  // k-major perm [32 c][1024 rb][64][8]
    const unsigned short* __restrict__ wcbp, // k-major perm [32 c][128 irb][64][8]
    const float* __restrict__ bz,
    const float* __restrict__ bh,
    __half2* __restrict__ av16,              // [M][H] half2(a,v)
    float2* __restrict__ chunkAV)            // [64][B][H]
{
    const int tid  = threadIdx.x;
    const int lane = tid & 63;
    const int w    = __builtin_amdgcn_readfirstlane(tid >> 6); // wave id 0..3
    const int r16  = lane & 15;
    const int q    = lane >> 4;

    // Bijective XCD swizzle (1024 % 8 == 0): swz = (bid&7)*128 + (bid>>3)
    const int bid = blockIdx.x;
    const int swz = (bid & 7) * 128 + (bid >> 3);
    const int nbg = swz & 7;                 // 0..7   (4 waves => nbw 0..31)
    const int mbw = swz >> 3;                // 0..127 (wave-row: 128 rows)
    const int nbw = nbg * 4 + w;             // 0..31  (64 int cols = 32 real)

    // per-lane fragment bases (contiguous 1KB per fragment)
    const unsigned short* gA = xbp  + (size_t)(mbw * 8) * 512 + lane * 8;
    const unsigned short* gB = wcbp + (size_t)(nbw * 4) * 512 + lane * 8;

    // A kblk stride = 1024 rb * 512 elems; B kblk stride = 128 irb * 512 elems.
#define LOADK(FA, FB, c) do { \
    const unsigned short* _a = gA + (size_t)(c) * 524288; \
    const unsigned short* _b = gB + (size_t)(c) * 65536; \
    _Pragma("unroll") \
    for (int m = 0; m < 8; ++m) FA[m] = *(const short8*)(_a + m * 512); \
    _Pragma("unroll") \
    for (int n = 0; n < 4; ++n) FB[n] = *(const short8*)(_b + n * 512); \
} while (0)

#define MFMA32(FA, FB) do { \
    __builtin_amdgcn_s_setprio(1); \
    _Pragma("unroll") \
    for (int m = 0; m < 8; ++m) \
        _Pragma("unroll") \
        for (int n = 0; n < 4; ++n) \
            acc[m][n] = __builtin_amdgcn_mfma_f32_16x16x32_bf16(FA[m], FB[n], acc[m][n], 0, 0, 0); \
    __builtin_amdgcn_s_setprio(0); \
} while (0)

    f32x4 acc[8][4] = {};
    short8 fa0[8], fb0[4], fa1[8], fb1[4];

    LOADK(fa0, fb0, 0);
    for (int cc = 0; cc < 32; cc += 2) {
        LOADK(fa1, fb1, cc + 1);             // prefetch next kblk while MFMA runs
        MFMA32(fa0, fb0);
        if (cc < 30) LOADK(fa0, fb0, cc + 2);
        MFMA32(fa1, fb1);
    }

    // ---------------- epilogue (identical math to R4; wave tile unchanged) ------
    // C/D layout: col = lane&15, row = q*4 + rr  [verified m89/m91].
    // acc[mf][2*gg+0] = z-GEMM, acc[mf][2*gg+1] = h-GEMM for real col
    //   ncol = nbw*32 + gg*16 + r16; rows m = mbw*128 + mf*16 + q*4 + rr.
    const int mrow0 = mbw * 128;
#pragma unroll
    for (int gg = 0; gg < 2; ++gg) {
        const int ncol = nbw * 32 + gg * 16 + r16;
        const float bzv = bz[ncol];
        const float bhv = bh[ncol];
#pragma unroll
        for (int hh = 0; hh < 2; ++hh) {     // two 64-row chunks per wave
            float CA = 1.0f, CV = 0.0f;
#pragma unroll
            for (int mm = 0; mm < 4; ++mm) {
                const int mf = hh * 4 + mm;
                float LA = 1.0f, LV = 0.0f;  // this lane's 4-row segment
#pragma unroll
                for (int rr = 0; rr < 4; ++rr) {
                    float kv = acc[mf][2 * gg + 0][rr] + bzv;
                    float hv = acc[mf][2 * gg + 1][rr] + bhv;
                    float tk = __expf(-fabsf(kv));
                    float ik = 1.0f / (1.0f + tk);
                    float sig = (kv >= 0.0f) ? ik : tk * ik;         // sigmoid(k)
                    float ac  = (kv >= 0.0f) ? tk * ik : ik;         // sigmoid(-k)
                    float th = __expf(-fabsf(hv));
                    float ih = 1.0f / (1.0f + th);
                    float gh = (hv >= 0.0f) ? (hv + 0.5f) : th * ih; // g(hb)
                    float vv = sig * gh;
                    const size_t m = (size_t)(mrow0 + mf * 16 + q * 4 + rr);
                    av16[m * H_ + ncol] = __floats2half2_rn(ac, vv);
                    LV = ac * LV + vv;       // ascending t composition
                    LA = ac * LA;
                }
                // order-preserving combine across q (lower lane index = earlier rows)
#pragma unroll
                for (int mask = 16; mask <= 32; mask <<= 1) {
                    float PA = __shfl_xor(LA, mask);
                    float PV = __shfl_xor(LV, mask);
                    if (lane & mask) { LV = LA * PV + LV; LA = LA * PA; }
                    else             { LV = PA * LV + PV; LA = PA * LA; }
                }
                CV = LA * CV + LV;
                CA = LA * CA;
            }
            if (q == 0) {
                const int cglob = mbw * 2 + hh;   // global 64-row chunk id 0..255
                chunkAV[(cglob & 63) * 4096 + (cglob >> 6) * 1024 + ncol] = make_float2(CA, CV);
            }
        }
    }
#undef LOADK
#undef MFMA32
}

// ---------------- scan pass3 (pass2 fused in): replay each chunk ----------------
// Each block handles one (b, c, 256-n-slice). The chunk entry state is computed
// in-block by scanning the c preceding chunk summaries (uniform loop count per
// block; 8B coalesced L2-resident loads) — removes the 16-block pass2 kernel,
// its launch gap, and the hstart round-trip.
__global__ __launch_bounds__(256) void scan_pass3(const __half2* __restrict__ av16,
                                                  const float2* __restrict__ chunkAV,
                                                  const float* __restrict__ h0,
                                                  float* __restrict__ out) {
    int g = blockIdx.x * blockDim.x + threadIdx.x;
    int n = g & (H_ - 1);
    int rest = g >> 10;
    int c = rest & 63;
    int b = rest >> 6;
    float x = h0[b * H_ + n];
    float h;
    if (x >= 0.0f) { h = x + 0.5f; }
    else { float t = __expf(x); h = t / (1.0f + t); }   // g(h0)
    for (int cc = 0; cc < c; ++cc) {                    // chunk-summary prefix scan
        float2 s = chunkAV[cc * 4096 + b * 1024 + n];
        h = s.x * h + s.y;
    }
    const __half2* base = av16 + ((size_t)(b * T_ + c * 64)) * H_ + n;
    float* obase = out + ((size_t)(b * T_ + c * 64)) * H_ + n;
#pragma unroll 8
    for (int t = 0; t < 64; ++t) {
        float2 p = __half22float2(base[(size_t)t * H_]);
        h = p.x * h + p.y;
        obase[(size_t)t * H_] = h;
    }
}

// ---------------- launch ----------------
extern "C" void kernel_launch(void* const* d_in, const int* in_sizes, int n_in,
                              void* d_out, int out_size, void* d_ws, size_t ws_size,
                              hipStream_t stream) {
    const float* x  = (const float*)d_in[0];   // [B,T,D]
    const float* h0 = (const float*)d_in[1];   // [B,H]
    const float* Wz = (const float*)d_in[2];   // [H,D]
    const float* bz = (const float*)d_in[3];   // [H]
    const float* Wh = (const float*)d_in[4];   // [H,D]
    const float* bh = (const float*)d_in[5];   // [H]
    float* out = (float*)d_out;

    // workspace layout (bytes):
    //   xbp  bf16 perm [M][D]      @ 0            33,554,432
    //   wcbp bf16 perm [2048][D]   @ 33554432      4,194,304
    //   av16 half2 [M][H]          @ 37748736     67,108,864
    //   chunkAV float2 [64][B][H]  @ 104857600     2,097,152
    char* ws = (char*)d_ws;
    unsigned short* xbp  = (unsigned short*)(ws);
    unsigned short* wcbp = (unsigned short*)(ws + 33554432);
    __half2* av16        = (__half2*)(ws + 37748736);
    float2* chunkAV      = (float2*)(ws + 104857600);

    // 2,097,152 (x) + 262,144 (wcb) lane-slots = 2,359,296 threads = 9216 blocks
    convert_all<<<9216, 256, 0, stream>>>(x, Wz, Wh, xbp, wcbp);

    dual_gemm_kernel<<<1024, 256, 0, stream>>>(xbp, wcbp, bz, bh, av16, chunkAV);

    scan_pass3<<<1024, 256, 0, stream>>>(av16, chunkAV, h0, out);
}

// Round 8
// 236.745 us; speedup vs baseline: 1.2323x; 1.0120x over previous
//
#include <hip/hip_runtime.h>
#include <hip/hip_bf16.h>
#include <hip/hip_fp16.h>

// Problem constants (from setup_inputs): B=4, T=4096, D=1024, H=1024
#define B_ 4
#define T_ 4096
#define D_ 1024
#define H_ 1024
#define M_ (B_ * T_)   // 16384

typedef __attribute__((ext_vector_type(8))) short short8;   // 8 bf16 = 4 VGPRs (MFMA A/B frag)
typedef __attribute__((ext_vector_type(4))) float f32x4;    // MFMA C/D frag

// ---------------- fp32 -> bf16 (RNE) ----------------
__device__ __forceinline__ unsigned short f2bf(float f) {
    unsigned int u = __float_as_uint(f);
    u += 0x7fffu + ((u >> 16) & 1u);
    return (unsigned short)(u >> 16);
}

// Convert + PERMUTE into k-major fragment-subtile-lane order.
// Fragment subtile = 16 rows x 32 k; lane l = (row = l&15, kpiece = l>>4), 8 bf16/lane.
// K-MAJOR linear order: slot(c, rb, l) = (c*NRB + rb)*64 + l  (c = kblk 0..31).
// => in the GEMM, one kblk's fragments for consecutive row-blocks are CONTIGUOUS
//    1KB-apart => base + immediate-offset loads, one pointer bump per kblk.
// wcb int-row interleave: int-row ir -> Wz row (ir>>5)*16+(ir&15) if (ir&31)<16
// else Wh row (ir>>5)*16+(ir&31)-16  (even/odd 16-col output frags = (z,h) pairs).
__global__ __launch_bounds__(256) void convert_all(
    const float* __restrict__ x, const float* __restrict__ wz, const float* __restrict__ wh,
    unsigned short* __restrict__ xbp, unsigned short* __restrict__ wcbp)
{
    int i = blockIdx.x * 256 + threadIdx.x;
    const float* srcrow;
    unsigned short* dst;
    if (i < 2097152) {               // x: 16384x1024 -> 2,097,152 lane-slots
        int l = i & 63, s = i >> 6;
        int c = s & 31, r = s >> 5;  // r = rowblk 0..1023
        int row = r * 16 + (l & 15);
        int k   = c * 32 + (l >> 4) * 8;
        srcrow = x + (size_t)row * D_ + k;
        dst = xbp + ((size_t)(c * 1024 + r) * 64 + l) * 8;   // k-major
    } else {                         // wcb: 2048x1024 -> 262,144 lane-slots
        int j = i - 2097152;
        int l = j & 63, s = j >> 6;
        int c = s & 31, r = s >> 5;  // r = int-rowblk 0..127
        int ir = r * 16 + (l & 15);  // interleaved int-row 0..2047
        int a = ir >> 5, wi = ir & 31;
        const float* m = (wi < 16) ? wz : wh;
        int srow = a * 16 + (wi & 15);
        int k = c * 32 + (l >> 4) * 8;
        srcrow = m + (size_t)srow * D_ + k;
        dst = wcbp + ((size_t)(c * 128 + r) * 64 + l) * 8;   // k-major
    }
    float4 f0 = ((const float4*)srcrow)[0];
    float4 f1 = ((const float4*)srcrow)[1];
    ushort4 u0, u1;
    u0.x = f2bf(f0.x); u0.y = f2bf(f0.y); u0.z = f2bf(f0.z); u0.w = f2bf(f0.w);
    u1.x = f2bf(f1.x); u1.y = f2bf(f1.y); u1.z = f2bf(f1.z); u1.w = f2bf(f1.w);
    ((ushort4*)dst)[0] = u0;
    ((ushort4*)dst)[1] = u1;
}

// ---------------- fused GEMM, flatmm-style: NO LDS, NO BARRIERS ----------------
// Both operands pre-permuted to fragment-lane order => every fragment is one
// coalesced 1KB global_load_dwordx4 per wave. Each wave independently streams:
//   [load kblk c+1 frags] [32 MFMA on kblk c]   (explicit 2-set ping-pong)
// Wave tile: 128(M) x 64(N_int = 32 real cols); acc[8][4] = 128 regs.
// Block = 4 waves sharing one 128-row A panel (L1 reuse), wave w takes
// nbw = nbg*4 + w. Grid 1024 = 128 mbw x 8 nbg.
// XCD swizzle: XCD x owns mbw in [16x,16x+16) -> its A slice = 4 MB, L2-resident.
// R8 change: epilogue interleaves gg=0/gg=1 per (row,rr) so each 128B av16
// line is write-complete back-to-back (kills partial-line eviction churn).
__global__ __launch_bounds__(256, 2) void dual_gemm_kernel(
    const unsigned short* __restrict__ xbp,  // k-major perm [32 c][1024 rb][64][8]
    const unsigned short* __restrict__ wcbp, // k-major perm [32 c][128 irb][64][8]
    const float* __restrict__ bz,
    const float* __restrict__ bh,
    __half2* __restrict__ av16,              // [M][H] half2(a,v)
    float2* __restrict__ chunkAV)            // [64][B][H]
{
    const int tid  = threadIdx.x;
    const int lane = tid & 63;
    const int w    = __builtin_amdgcn_readfirstlane(tid >> 6); // wave id 0..3
    const int r16  = lane & 15;
    const int q    = lane >> 4;

    // Bijective XCD swizzle (1024 % 8 == 0): swz = (bid&7)*128 + (bid>>3)
    const int bid = blockIdx.x;
    const int swz = (bid & 7) * 128 + (bid >> 3);
    const int nbg = swz & 7;                 // 0..7   (4 waves => nbw 0..31)
    const int mbw = swz >> 3;                // 0..127 (wave-row: 128 rows)
    const int nbw = nbg * 4 + w;             // 0..31  (64 int cols = 32 real)

    // per-lane fragment bases (contiguous 1KB per fragment)
    const unsigned short* gA = xbp  + (size_t)(mbw * 8) * 512 + lane * 8;
    const unsigned short* gB = wcbp + (size_t)(nbw * 4) * 512 + lane * 8;

    // A kblk stride = 1024 rb * 512 elems; B kblk stride = 128 irb * 512 elems.
#define LOADK(FA, FB, c) do { \
    const unsigned short* _a = gA + (size_t)(c) * 524288; \
    const unsigned short* _b = gB + (size_t)(c) * 65536; \
    _Pragma("unroll") \
    for (int m = 0; m < 8; ++m) FA[m] = *(const short8*)(_a + m * 512); \
    _Pragma("unroll") \
    for (int n = 0; n < 4; ++n) FB[n] = *(const short8*)(_b + n * 512); \
} while (0)

#define MFMA32(FA, FB) do { \
    __builtin_amdgcn_s_setprio(1); \
    _Pragma("unroll") \
    for (int m = 0; m < 8; ++m) \
        _Pragma("unroll") \
        for (int n = 0; n < 4; ++n) \
            acc[m][n] = __builtin_amdgcn_mfma_f32_16x16x32_bf16(FA[m], FB[n], acc[m][n], 0, 0, 0); \
    __builtin_amdgcn_s_setprio(0); \
} while (0)

    f32x4 acc[8][4] = {};
    short8 fa0[8], fb0[4], fa1[8], fb1[4];

    LOADK(fa0, fb0, 0);
    for (int cc = 0; cc < 32; cc += 2) {
        LOADK(fa1, fb1, cc + 1);             // prefetch next kblk while MFMA runs
        MFMA32(fa0, fb0);
        if (cc < 30) LOADK(fa0, fb0, cc + 2);
        MFMA32(fa1, fb1);
    }

    // ---------------- epilogue (gg-interleaved stores; same math as R5) -------
    // C/D layout: col = lane&15, row = q*4 + rr  [verified m89/m91].
    // acc[mf][0/1] = z/h GEMM for col ncol0; acc[mf][2/3] = z/h for ncol0+16.
    const int mrow0 = mbw * 128;
    const int ncol0 = nbw * 32 + r16;
    const float bzv0 = bz[ncol0],      bhv0 = bh[ncol0];
    const float bzv1 = bz[ncol0 + 16], bhv1 = bh[ncol0 + 16];
#pragma unroll
    for (int hh = 0; hh < 2; ++hh) {         // two 64-row chunks per wave
        float CA0 = 1.0f, CV0 = 0.0f, CA1 = 1.0f, CV1 = 0.0f;
#pragma unroll
        for (int mm = 0; mm < 4; ++mm) {
            const int mf = hh * 4 + mm;
            float LA0 = 1.0f, LV0 = 0.0f, LA1 = 1.0f, LV1 = 0.0f;
#pragma unroll
            for (int rr = 0; rr < 4; ++rr) {
                const size_t m = (size_t)(mrow0 + mf * 16 + q * 4 + rr);
                // ---- gg = 0 ----
                {
                    float kv = acc[mf][0][rr] + bzv0;
                    float hv = acc[mf][1][rr] + bhv0;
                    float tk = __expf(-fabsf(kv));
                    float ik = 1.0f / (1.0f + tk);
                    float sig = (kv >= 0.0f) ? ik : tk * ik;         // sigmoid(k)
                    float ac  = (kv >= 0.0f) ? tk * ik : ik;         // sigmoid(-k)
                    float th = __expf(-fabsf(hv));
                    float ih = 1.0f / (1.0f + th);
                    float gh = (hv >= 0.0f) ? (hv + 0.5f) : th * ih; // g(hb)
                    float vv = sig * gh;
                    av16[m * H_ + ncol0] = __floats2half2_rn(ac, vv);
                    LV0 = ac * LV0 + vv;     // ascending t composition
                    LA0 = ac * LA0;
                }
                // ---- gg = 1 (adjacent store completes the 128B line) ----
                {
                    float kv = acc[mf][2][rr] + bzv1;
                    float hv = acc[mf][3][rr] + bhv1;
                    float tk = __expf(-fabsf(kv));
                    float ik = 1.0f / (1.0f + tk);
                    float sig = (kv >= 0.0f) ? ik : tk * ik;
                    float ac  = (kv >= 0.0f) ? tk * ik : ik;
                    float th = __expf(-fabsf(hv));
                    float ih = 1.0f / (1.0f + th);
                    float gh = (hv >= 0.0f) ? (hv + 0.5f) : th * ih;
                    float vv = sig * gh;
                    av16[m * H_ + ncol0 + 16] = __floats2half2_rn(ac, vv);
                    LV1 = ac * LV1 + vv;
                    LA1 = ac * LA1;
                }
            }
            // order-preserving combine across q (lower lane index = earlier rows)
#pragma unroll
            for (int mask = 16; mask <= 32; mask <<= 1) {
                float PA0 = __shfl_xor(LA0, mask);
                float PV0 = __shfl_xor(LV0, mask);
                float PA1 = __shfl_xor(LA1, mask);
                float PV1 = __shfl_xor(LV1, mask);
                if (lane & mask) {
                    LV0 = LA0 * PV0 + LV0; LA0 = LA0 * PA0;
                    LV1 = LA1 * PV1 + LV1; LA1 = LA1 * PA1;
                } else {
                    LV0 = PA0 * LV0 + PV0; LA0 = PA0 * LA0;
                    LV1 = PA1 * LV1 + PV1; LA1 = PA1 * LA1;
                }
            }
            CV0 = LA0 * CV0 + LV0; CA0 = LA0 * CA0;
            CV1 = LA1 * CV1 + LV1; CA1 = LA1 * CA1;
        }
        if (q == 0) {
            const int cglob = mbw * 2 + hh;  // global 64-row chunk id 0..255
            const int base = (cglob & 63) * 4096 + (cglob >> 6) * 1024;
            chunkAV[base + ncol0]      = make_float2(CA0, CV0);
            chunkAV[base + ncol0 + 16] = make_float2(CA1, CV1);
        }
    }
#undef LOADK
#undef MFMA32
}

// ---------------- scan pass3 (pass2 fused in): replay each chunk ----------------
// Each block handles one (b, c, 256-n-slice). The chunk entry state is computed
// in-block by scanning the c preceding chunk summaries (uniform loop count per
// block; 8B coalesced L2-resident loads).
__global__ __launch_bounds__(256) void scan_pass3(const __half2* __restrict__ av16,
                                                  const float2* __restrict__ chunkAV,
                                                  const float* __restrict__ h0,
                                                  float* __restrict__ out) {
    int g = blockIdx.x * blockDim.x + threadIdx.x;
    int n = g & (H_ - 1);
    int rest = g >> 10;
    int c = rest & 63;
    int b = rest >> 6;
    float x = h0[b * H_ + n];
    float h;
    if (x >= 0.0f) { h = x + 0.5f; }
    else { float t = __expf(x); h = t / (1.0f + t); }   // g(h0)
    for (int cc = 0; cc < c; ++cc) {                    // chunk-summary prefix scan
        float2 s = chunkAV[cc * 4096 + b * 1024 + n];
        h = s.x * h + s.y;
    }
    const __half2* base = av16 + ((size_t)(b * T_ + c * 64)) * H_ + n;
    float* obase = out + ((size_t)(b * T_ + c * 64)) * H_ + n;
#pragma unroll 8
    for (int t = 0; t < 64; ++t) {
        float2 p = __half22float2(base[(size_t)t * H_]);
        h = p.x * h + p.y;
        obase[(size_t)t * H_] = h;
    }
}

// ---------------- launch ----------------
extern "C" void kernel_launch(void* const* d_in, const int* in_sizes, int n_in,
                              void* d_out, int out_size, void* d_ws, size_t ws_size,
                              hipStream_t stream) {
    const float* x  = (const float*)d_in[0];   // [B,T,D]
    const float* h0 = (const float*)d_in[1];   // [B,H]
    const float* Wz = (const float*)d_in[2];   // [H,D]
    const float* bz = (const float*)d_in[3];   // [H]
    const float* Wh = (const float*)d_in[4];   // [H,D]
    const float* bh = (const float*)d_in[5];   // [H]
    float* out = (float*)d_out;

    // workspace layout (bytes):
    //   xbp  bf16 perm [M][D]      @ 0            33,554,432
    //   wcbp bf16 perm [2048][D]   @ 33554432      4,194,304
    //   av16 half2 [M][H]          @ 37748736     67,108,864
    //   chunkAV float2 [64][B][H]  @ 104857600     2,097,152
    char* ws = (char*)d_ws;
    unsigned short* xbp  = (unsigned short*)(ws);
    unsigned short* wcbp = (unsigned short*)(ws + 33554432);
    __half2* av16        = (__half2*)(ws + 37748736);
    float2* chunkAV      = (float2*)(ws + 104857600);

    // 2,097,152 (x) + 262,144 (wcb) lane-slots = 2,359,296 threads = 9216 blocks
    convert_all<<<9216, 256, 0, stream>>>(x, Wz, Wh, xbp, wcbp);

    dual_gemm_kernel<<<1024, 256, 0, stream>>>(xbp, wcbp, bz, bh, av16, chunkAV);

    scan_pass3<<<1024, 256, 0, stream>>>(av16, chunkAV, h0, out);
}